// Round 1
// baseline (247.732 us; speedup 1.0000x reference)
//
#include <hip/hip_runtime.h>
#include <hip/hip_bf16.h>
#include <math.h>

#define NPTS 100000
#define NPAD 100096      // 782*128
#define PDIM 256
#define KCOMP 64
#define CCOLS 1024       // KCOMP*16

typedef float v4f __attribute__((ext_vector_type(4)));
typedef __bf16 v8bf __attribute__((ext_vector_type(8)));

// ---------- async global->LDS (16B per lane) ----------
__device__ __forceinline__ void gload_lds16(const void* g, void* lds) {
    __builtin_amdgcn_global_load_lds(
        (const __attribute__((address_space(1))) void*)(uintptr_t)g,
        (__attribute__((address_space(3))) void*)(uint32_t)(uintptr_t)lds,
        16, 0, 0);
}

// ---------- kernel 1: log_softmax(pi), 1 block x 64 threads ----------
__global__ void prep_pi(const float* __restrict__ pi, float* __restrict__ logpi) {
    int t = threadIdx.x;
    float v = pi[t];
    float m = v;
    for (int off = 32; off; off >>= 1) m = fmaxf(m, __shfl_xor(m, off));
    float e = __expf(v - m);
    float s = e;
    for (int off = 32; off; off >>= 1) s += __shfl_xor(s, off);
    logpi[t] = v - m - logf(s);
}

// ---------- kernel 2: per-component D = I + M^T M, Cholesky, B = M Linv^T ----------
__global__ __launch_bounds__(256) void prep_comp(const float* __restrict__ M,
                                                 const float* __restrict__ logpi,
                                                 __bf16* __restrict__ Bt,
                                                 float* __restrict__ cvec,
                                                 float logSA) {
    __shared__ float Ml[256][16];
    __shared__ float S[16][16];
    __shared__ float Li[16][16];
    const int k = blockIdx.x, t = threadIdx.x;

    // load M[k]: row p = t, 16 floats contiguous
    const float4* src = (const float4*)(M + (size_t)k * 4096 + (size_t)t * 16);
    float4 a0 = src[0], a1 = src[1], a2 = src[2], a3 = src[3];
    ((float4*)Ml[t])[0] = a0; ((float4*)Ml[t])[1] = a1;
    ((float4*)Ml[t])[2] = a2; ((float4*)Ml[t])[3] = a3;
    __syncthreads();

    // S = I + M^T M : thread (r,c)
    {
        int r = t >> 4, c = t & 15;
        float s = (r == c) ? 1.0f : 0.0f;
        for (int p = 0; p < 256; ++p) s += Ml[p][r] * Ml[p][c];
        S[r][c] = s;
    }
    __syncthreads();

    if (t == 0) {
        // Cholesky in place (lower), logdet
        float ldet = 0.0f;
        for (int j = 0; j < 16; ++j) {
            float d = S[j][j];
            for (int q = 0; q < j; ++q) d -= S[j][q] * S[j][q];
            d = sqrtf(d);
            S[j][j] = d;
            ldet += logf(d);
            float inv = 1.0f / d;
            for (int i = j + 1; i < 16; ++i) {
                float v = S[i][j];
                for (int q = 0; q < j; ++q) v -= S[i][q] * S[j][q];
                S[i][j] = v * inv;
            }
        }
        ldet *= 2.0f;
        // Linv (lower-triangular inverse of L)
        for (int j = 0; j < 16; ++j) {
            Li[j][j] = 1.0f / S[j][j];
            for (int i = j + 1; i < 16; ++i) {
                float v = 0.0f;
                for (int q = j; q < i; ++q) v -= S[i][q] * Li[q][j];
                Li[i][j] = v / S[i][i];
            }
            for (int i = 0; i < j; ++i) Li[i][j] = 0.0f;
        }
        cvec[k] = logSA - 0.5f * ldet + logpi[k];
    }
    __syncthreads();

    // B[p][r] = sum_s M[p][s] * Linv[r][s]  (s<=r), store transposed bf16: Bt[k*16+r][p]
    for (int r = 0; r < 16; ++r) {
        float acc = 0.0f;
        for (int s = 0; s <= r; ++s) acc += Ml[t][s] * Li[r][s];
        Bt[(size_t)(k * 16 + r) * 256 + t] = (__bf16)acc;
    }
}

// ---------- kernel 3: X fp32 -> bf16, padded rows zeroed ----------
__global__ __launch_bounds__(256) void convert_X(const float* __restrict__ X,
                                                 __bf16* __restrict__ Xb) {
    size_t i = ((size_t)blockIdx.x * 256 + threadIdx.x) * 8;
    int n = (int)(i >> 8);
    v8bf o;
    if (n < NPTS) {
        const float4* s4 = (const float4*)(X + i);
        float4 a = s4[0], b = s4[1];
        o[0] = (__bf16)a.x; o[1] = (__bf16)a.y; o[2] = (__bf16)a.z; o[3] = (__bf16)a.w;
        o[4] = (__bf16)b.x; o[5] = (__bf16)b.y; o[6] = (__bf16)b.z; o[7] = (__bf16)b.w;
    } else {
        for (int j = 0; j < 8; ++j) o[j] = (__bf16)0.0f;
    }
    *(v8bf*)(Xb + i) = o;
}

// ---------- kernel 4: GEMM + fused quad/density epilogue ----------
// C[n, c] = sum_p Xb[n,p]*Bt[c,p]; quad[n,k] = sum_{r<16} C[n,k*16+r]^2
// dens[k][n] = cvec[k] - 128*log(1-quad)
__global__ __launch_bounds__(256) void gemm_density(const __bf16* __restrict__ Xb,
                                                    const __bf16* __restrict__ Bt,
                                                    const float* __restrict__ cvec,
                                                    float* __restrict__ dens) {
    __shared__ __bf16 As[128 * 32];
    __shared__ __bf16 Bs[128 * 32];
    const int tid = threadIdx.x;
    const int rt = blockIdx.x >> 3;
    const int ct = blockIdx.x & 7;
    const int row0 = rt << 7, col0 = ct << 7;
    const int wave = tid >> 6, lane = tid & 63;
    const int wm = wave >> 1, wn = wave & 1;
    const int lo = lane & 15, hi = lane >> 4;

    v4f acc[4][4] = {};

    // staging: thread -> 16B: row = tid>>2 (0..63), k-offset = (tid&3)*8
    const int srow = tid >> 2;
    const int skk = (tid & 3) << 3;
    const size_t gA = (size_t)(row0 + srow) * 256 + skk;
    const size_t gB = (size_t)(col0 + srow) * 256 + skk;
    __bf16* ldsA = As + ((tid >> 6) << 9);  // wave-uniform base (wave*1024 B)
    __bf16* ldsB = Bs + ((tid >> 6) << 9);

    for (int kt = 0; kt < 8; ++kt) {
        const int kb = kt << 5;
        __syncthreads();  // previous compute done with LDS
        gload_lds16(Xb + gA + kb,            ldsA);
        gload_lds16(Xb + gA + kb + 64 * 256, (char*)ldsA + 4096);
        gload_lds16(Bt + gB + kb,            ldsB);
        gload_lds16(Bt + gB + kb + 64 * 256, (char*)ldsB + 4096);
        __syncthreads();  // drains vmcnt -> LDS ready

        v8bf af[4], bg[4];
#pragma unroll
        for (int m = 0; m < 4; ++m)
            af[m] = *(const v8bf*)&As[(wm * 64 + m * 16 + lo) * 32 + hi * 8];
#pragma unroll
        for (int n = 0; n < 4; ++n)
            bg[n] = *(const v8bf*)&Bs[(wn * 64 + n * 16 + lo) * 32 + hi * 8];
#pragma unroll
        for (int m = 0; m < 4; ++m)
#pragma unroll
            for (int n = 0; n < 4; ++n)
                acc[m][n] = __builtin_amdgcn_mfma_f32_16x16x32_bf16(af[m], bg[n], acc[m][n], 0, 0, 0);
    }

    // epilogue: quad per (row, 16-col group) then density
#pragma unroll
    for (int m = 0; m < 4; ++m) {
        const int rowb = row0 + wm * 64 + m * 16 + hi * 4;
#pragma unroll
        for (int n = 0; n < 4; ++n) {
            const int kc = (col0 >> 4) + wn * 4 + n;
            v4f q = acc[m][n] * acc[m][n];
#pragma unroll
            for (int off = 1; off < 16; off <<= 1) {
                v4f t;
                t[0] = __shfl_xor(q[0], off);
                t[1] = __shfl_xor(q[1], off);
                t[2] = __shfl_xor(q[2], off);
                t[3] = __shfl_xor(q[3], off);
                q += t;
            }
            if (lo < 4) {
                const float quad = q[lo];
                const float d = cvec[kc] - 128.0f * logf(1.0f - quad);
                dens[(size_t)kc * NPAD + rowb + lo] = d;
            }
        }
    }
}

// ---------- kernel 5: logsumexp over k, global sum ----------
__global__ __launch_bounds__(256) void reduce_ll(const float* __restrict__ dens,
                                                 float* __restrict__ out) {
    const int n = blockIdx.x * 256 + threadIdx.x;
    float local = 0.0f;
    if (n < NPTS) {
        float m = dens[n];
        float s = 1.0f;
        for (int k = 1; k < 64; ++k) {
            float d = dens[(size_t)k * NPAD + n];
            if (d > m) { s = s * __expf(m - d) + 1.0f; m = d; }
            else       { s += __expf(d - m); }
        }
        local = m + logf(s);
    }
    for (int off = 32; off; off >>= 1) local += __shfl_down(local, off);
    __shared__ float part[4];
    const int w = threadIdx.x >> 6, lane = threadIdx.x & 63;
    if (lane == 0) part[w] = local;
    __syncthreads();
    if (threadIdx.x == 0) atomicAdd(out, part[0] + part[1] + part[2] + part[3]);
}

extern "C" void kernel_launch(void* const* d_in, const int* in_sizes, int n_in,
                              void* d_out, int out_size, void* d_ws, size_t ws_size,
                              hipStream_t stream) {
    const float* X  = (const float*)d_in[0];
    const float* M  = (const float*)d_in[1];
    const float* pi = (const float*)d_in[2];
    float* out = (float*)d_out;

    char* ws = (char*)d_ws;
    __bf16* Xb    = (__bf16*)ws;                          // 100096*256*2 = 51,249,152
    __bf16* Bt    = (__bf16*)(ws + 51249152);             // 1024*256*2   =    524,288
    float*  dens  = (float*)(ws + 51773440);              // 64*100096*4  = 25,624,576
    float*  logpi = (float*)(ws + 77398016);              // 256 B
    float*  cvec  = (float*)(ws + 77398272);              // 256 B

    const double half_p = 128.0;
    const float logSA = (float)(lgamma(half_p) - log(2.0) - half_p * log(M_PI));

    hipMemsetAsync(d_out, 0, sizeof(float), stream);
    prep_pi<<<1, 64, 0, stream>>>(pi, logpi);
    prep_comp<<<64, 256, 0, stream>>>(M, logpi, Bt, cvec, logSA);
    convert_X<<<12512, 256, 0, stream>>>(X, Xb);
    gemm_density<<<6256, 256, 0, stream>>>(Xb, Bt, cvec, dens);
    reduce_ll<<<391, 256, 0, stream>>>(dens, out);
}

// Round 2
// 223.744 us; speedup vs baseline: 1.1072x; 1.1072x over previous
//
#include <hip/hip_runtime.h>
#include <hip/hip_bf16.h>
#include <math.h>

#define NPTS 100000
#define NPAD 100352      // 784*128 (784 row tiles: divisible by 8 XCDs)
#define PDIM 256
#define KCOMP 64

typedef float v4f __attribute__((ext_vector_type(4)));
typedef __bf16 v8bf __attribute__((ext_vector_type(8)));

// ---------- async global->LDS (16B per lane) ----------
__device__ __forceinline__ void gload_lds16(const void* g, void* lds) {
    __builtin_amdgcn_global_load_lds(
        (const __attribute__((address_space(1))) void*)(uintptr_t)g,
        (__attribute__((address_space(3))) void*)(uint32_t)(uintptr_t)lds,
        16, 0, 0);
}

// ---------- kernel 1: log_softmax(pi), 1 block x 64 threads ----------
__global__ void prep_pi(const float* __restrict__ pi, float* __restrict__ logpi) {
    int t = threadIdx.x;
    float v = pi[t];
    float m = v;
    for (int off = 32; off; off >>= 1) m = fmaxf(m, __shfl_xor(m, off));
    float e = __expf(v - m);
    float s = e;
    for (int off = 32; off; off >>= 1) s += __shfl_xor(s, off);
    logpi[t] = v - m - logf(s);
}

// ---------- kernel 2: per-component D = I + M^T M, Cholesky, B = M Linv^T ----------
__global__ __launch_bounds__(256) void prep_comp(const float* __restrict__ M,
                                                 const float* __restrict__ logpi,
                                                 __bf16* __restrict__ Bt,
                                                 float* __restrict__ cvec,
                                                 float logSA) {
    __shared__ float Ml[256][16];
    __shared__ float S[16][16];
    __shared__ float Li[16][16];
    const int k = blockIdx.x, t = threadIdx.x;

    const float4* src = (const float4*)(M + (size_t)k * 4096 + (size_t)t * 16);
    float4 a0 = src[0], a1 = src[1], a2 = src[2], a3 = src[3];
    ((float4*)Ml[t])[0] = a0; ((float4*)Ml[t])[1] = a1;
    ((float4*)Ml[t])[2] = a2; ((float4*)Ml[t])[3] = a3;
    __syncthreads();

    {
        int r = t >> 4, c = t & 15;
        float s = (r == c) ? 1.0f : 0.0f;
        for (int p = 0; p < 256; ++p) s += Ml[p][r] * Ml[p][c];
        S[r][c] = s;
    }
    __syncthreads();

    if (t == 0) {
        float ldet = 0.0f;
        for (int j = 0; j < 16; ++j) {
            float d = S[j][j];
            for (int q = 0; q < j; ++q) d -= S[j][q] * S[j][q];
            d = sqrtf(d);
            S[j][j] = d;
            ldet += logf(d);
            float inv = 1.0f / d;
            for (int i = j + 1; i < 16; ++i) {
                float v = S[i][j];
                for (int q = 0; q < j; ++q) v -= S[i][q] * S[j][q];
                S[i][j] = v * inv;
            }
        }
        ldet *= 2.0f;
        for (int j = 0; j < 16; ++j) {
            Li[j][j] = 1.0f / S[j][j];
            for (int i = j + 1; i < 16; ++i) {
                float v = 0.0f;
                for (int q = j; q < i; ++q) v -= S[i][q] * Li[q][j];
                Li[i][j] = v / S[i][i];
            }
            for (int i = 0; i < j; ++i) Li[i][j] = 0.0f;
        }
        cvec[k] = logSA - 0.5f * ldet + logpi[k];
    }
    __syncthreads();

    for (int r = 0; r < 16; ++r) {
        float acc = 0.0f;
        for (int s = 0; s <= r; ++s) acc += Ml[t][s] * Li[r][s];
        Bt[(size_t)(k * 16 + r) * 256 + t] = (__bf16)acc;
    }
}

// ---------- kernel 3: X fp32 -> bf16, padded rows zeroed ----------
__global__ __launch_bounds__(256) void convert_X(const float* __restrict__ X,
                                                 __bf16* __restrict__ Xb) {
    size_t i = ((size_t)blockIdx.x * 256 + threadIdx.x) * 8;
    int n = (int)(i >> 8);
    v8bf o;
    if (n < NPTS) {
        const float4* s4 = (const float4*)(X + i);
        float4 a = s4[0], b = s4[1];
        o[0] = (__bf16)a.x; o[1] = (__bf16)a.y; o[2] = (__bf16)a.z; o[3] = (__bf16)a.w;
        o[4] = (__bf16)b.x; o[5] = (__bf16)b.y; o[6] = (__bf16)b.z; o[7] = (__bf16)b.w;
    } else {
        for (int j = 0; j < 8; ++j) o[j] = (__bf16)0.0f;
    }
    *(v8bf*)(Xb + i) = o;
}

// ---------- kernel 4: GEMM + fused quad/density epilogue (2-phase dbuf) ----------
__global__ __launch_bounds__(256) void gemm_density(const __bf16* __restrict__ Xb,
                                                    const __bf16* __restrict__ Bt,
                                                    const float* __restrict__ cvec,
                                                    float* __restrict__ dens) {
    __shared__ __bf16 As[2][128 * 32];
    __shared__ __bf16 Bs[2][128 * 32];
    // XCD-swizzle: all 8 col-tiles of one row-tile land on the same XCD (bid&7)
    const int bid = blockIdx.x;
    const int xcd = bid & 7, j = bid >> 3;
    const int rt = xcd + ((j >> 3) << 3);   // 0..783
    const int ct = j & 7;
    const int row0 = rt << 7, col0 = ct << 7;
    const int tid = threadIdx.x;
    const int wave = tid >> 6, lane = tid & 63;
    const int wm = wave >> 1, wn = wave & 1;
    const int lo = lane & 15, hi = lane >> 4;

    v4f acc[4][4] = {};

    const int srow = tid >> 2;              // 0..63
    const int skk = (tid & 3) << 3;
    const size_t gA = (size_t)(row0 + srow) * 256 + skk;
    const size_t gB = (size_t)(col0 + srow) * 256 + skk;
    const int ldsoff = wave << 9;           // wave-uniform: wave*512 elements (1024B)

#define STAGE(buf, kt) do {                                             \
    const int kb_ = (kt) << 5;                                          \
    gload_lds16(Xb + gA + kb_,            As[buf] + ldsoff);            \
    gload_lds16(Xb + gA + kb_ + 64*256,   As[buf] + ldsoff + 2048);     \
    gload_lds16(Bt + gB + kb_,            Bs[buf] + ldsoff);            \
    gload_lds16(Bt + gB + kb_ + 64*256,   Bs[buf] + ldsoff + 2048);     \
} while (0)

    STAGE(0, 0);
    asm volatile("s_waitcnt vmcnt(0)" ::: "memory");
    __syncthreads();

    int cur = 0;
#pragma unroll
    for (int kt = 0; kt < 8; ++kt) {
        if (kt < 7) STAGE(cur ^ 1, kt + 1);   // prefetch next K-step while computing

        v8bf af[4], bg[4];
#pragma unroll
        for (int m = 0; m < 4; ++m)
            af[m] = *(const v8bf*)&As[cur][(wm * 64 + m * 16 + lo) * 32 + hi * 8];
#pragma unroll
        for (int n = 0; n < 4; ++n)
            bg[n] = *(const v8bf*)&Bs[cur][(wn * 64 + n * 16 + lo) * 32 + hi * 8];
#pragma unroll
        for (int m = 0; m < 4; ++m)
#pragma unroll
            for (int n = 0; n < 4; ++n)
                acc[m][n] = __builtin_amdgcn_mfma_f32_16x16x32_bf16(af[m], bg[n], acc[m][n], 0, 0, 0);

        if (kt < 7) {
            asm volatile("s_waitcnt vmcnt(0)" ::: "memory");
            __syncthreads();
            cur ^= 1;
        }
    }
#undef STAGE

    // epilogue: quad per (row, 16-col group) then density
#pragma unroll
    for (int m = 0; m < 4; ++m) {
        const int rowb = row0 + wm * 64 + m * 16 + hi * 4;
#pragma unroll
        for (int n = 0; n < 4; ++n) {
            const int kc = (col0 >> 4) + wn * 4 + n;
            v4f q = acc[m][n] * acc[m][n];
#pragma unroll
            for (int off = 1; off < 16; off <<= 1) {
                v4f t;
                t[0] = __shfl_xor(q[0], off);
                t[1] = __shfl_xor(q[1], off);
                t[2] = __shfl_xor(q[2], off);
                t[3] = __shfl_xor(q[3], off);
                q += t;
            }
            if (lo < 4) {
                const float quad = q[lo];
                const float d = cvec[kc] - 128.0f * logf(1.0f - quad);
                dens[(size_t)kc * NPAD + rowb + lo] = d;
            }
        }
    }
}

// ---------- kernel 5: logsumexp over k, global sum (branchless online) ----------
__global__ __launch_bounds__(256) void reduce_ll(const float* __restrict__ dens,
                                                 float* __restrict__ out) {
    const int n = blockIdx.x * 256 + threadIdx.x;
    float local = 0.0f;
    if (n < NPTS) {
        float m = dens[n];
        float s = 1.0f;
        for (int k = 1; k < 64; ++k) {
            float d = dens[(size_t)k * NPAD + n];
            float mn = fmaxf(m, d);
            s = s * __expf(m - mn) + __expf(d - mn);
            m = mn;
        }
        local = m + logf(s);
    }
    for (int off = 32; off; off >>= 1) local += __shfl_down(local, off);
    __shared__ float part[4];
    const int w = threadIdx.x >> 6, lane = threadIdx.x & 63;
    if (lane == 0) part[w] = local;
    __syncthreads();
    if (threadIdx.x == 0) atomicAdd(out, part[0] + part[1] + part[2] + part[3]);
}

extern "C" void kernel_launch(void* const* d_in, const int* in_sizes, int n_in,
                              void* d_out, int out_size, void* d_ws, size_t ws_size,
                              hipStream_t stream) {
    const float* X  = (const float*)d_in[0];
    const float* M  = (const float*)d_in[1];
    const float* pi = (const float*)d_in[2];
    float* out = (float*)d_out;

    char* ws = (char*)d_ws;
    __bf16* Xb    = (__bf16*)ws;                          // 100352*256*2 = 51,380,224
    __bf16* Bt    = (__bf16*)(ws + 51380224);             // 1024*256*2   =    524,288
    float*  dens  = (float*)(ws + 51904512);              // 64*100352*4  = 25,690,112
    float*  logpi = (float*)(ws + 77594624);              // 256 B
    float*  cvec  = (float*)(ws + 77594880);              // 256 B

    const double half_p = 128.0;
    const float logSA = (float)(lgamma(half_p) - log(2.0) - half_p * log(M_PI));

    hipMemsetAsync(d_out, 0, sizeof(float), stream);
    prep_pi<<<1, 64, 0, stream>>>(pi, logpi);
    prep_comp<<<64, 256, 0, stream>>>(M, logpi, Bt, cvec, logSA);
    convert_X<<<12544, 256, 0, stream>>>(X, Xb);          // 100352*256/2048
    gemm_density<<<6272, 256, 0, stream>>>(Xb, Bt, cvec, dens);   // 784*8 tiles
    reduce_ll<<<391, 256, 0, stream>>>(dens, out);
}

// Round 3
// 175.469 us; speedup vs baseline: 1.4118x; 1.2751x over previous
//
#include <hip/hip_runtime.h>
#include <hip/hip_bf16.h>
#include <math.h>

#define NPTS 100000
#define NPAD 100352      // 784*128 (784 row tiles: divisible by 8 XCDs)
#define PDIM 256
#define KCOMP 64

typedef float v4f __attribute__((ext_vector_type(4)));
typedef __bf16 v8bf __attribute__((ext_vector_type(8)));

// ---------- async global->LDS (16B per lane; LDS base wave-uniform) ----------
__device__ __forceinline__ void gload_lds16(const void* g, void* lds) {
    __builtin_amdgcn_global_load_lds(
        (const __attribute__((address_space(1))) void*)(uintptr_t)g,
        (__attribute__((address_space(3))) void*)(uint32_t)(uintptr_t)lds,
        16, 0, 0);
}

// ---------- kernel 1: per-component prep ----------
// D = I + M^T M ; parallel Cholesky D = L L^T ; Bt[k*16+r][p] = (L^{-1} M^T)[r][p]
// stored PRE-SWIZZLED: element index p ^= ((crow&7)<<3). cvec[k] = logSA - sum log L_jj + logpi[k].
__global__ __launch_bounds__(256) void prep_comp(const float* __restrict__ M,
                                                 const float* __restrict__ pi,
                                                 __bf16* __restrict__ Bt,
                                                 float* __restrict__ cvec,
                                                 float logSA) {
    __shared__ float Ml[256][16];
    __shared__ float S[16][17];
    __shared__ float sh_logpi;
    const int k = blockIdx.x, t = threadIdx.x;

    // load row t of M[k] into registers + LDS
    const float4* src = (const float4*)(M + (size_t)k * 4096 + (size_t)t * 16);
    float4 a0 = src[0], a1 = src[1], a2 = src[2], a3 = src[3];
    ((float4*)Ml[t])[0] = a0; ((float4*)Ml[t])[1] = a1;
    ((float4*)Ml[t])[2] = a2; ((float4*)Ml[t])[3] = a3;

    // log_softmax(pi)[k] computed by wave 0
    if (t < 64) {
        float v = pi[t];
        float mx = v;
        for (int off = 32; off; off >>= 1) mx = fmaxf(mx, __shfl_xor(mx, off));
        float e = __expf(v - mx);
        float s = e;
        for (int off = 32; off; off >>= 1) s += __shfl_xor(s, off);
        if (t == 0) sh_logpi = pi[k] - mx - logf(s);
    }
    __syncthreads();

    // S = I + M^T M (thread (r,c))
    {
        int r = t >> 4, c = t & 15;
        float s = (r == c) ? 1.0f : 0.0f;
        for (int p = 0; p < 256; ++p) s += Ml[p][r] * Ml[p][c];
        S[r][c] = s;
    }
    __syncthreads();

    // parallel right-looking Cholesky (lower in S)
    for (int j = 0; j < 16; ++j) {
        if (t == 0) S[j][j] = sqrtf(S[j][j]);
        __syncthreads();
        if (t > j && t < 16) S[t][j] = S[t][j] / S[j][j];
        __syncthreads();
        {
            int r = t >> 4, c = t & 15;
            if (r > j && c > j && c <= r) S[r][c] -= S[r][j] * S[c][j];
        }
        __syncthreads();
    }

    if (t == 0) {
        float ldet = 0.0f;
        for (int j = 0; j < 16; ++j) ldet += logf(S[j][j]);
        cvec[k] = logSA - ldet + sh_logpi;   // logSA - 0.5*logdet + logpi
    }

    // forward substitution: y = L^{-1} m_t (m_t in registers, L broadcast from LDS)
    float m[16] = {a0.x, a0.y, a0.z, a0.w, a1.x, a1.y, a1.z, a1.w,
                   a2.x, a2.y, a2.z, a2.w, a3.x, a3.y, a3.z, a3.w};
    float y[16];
#pragma unroll
    for (int r = 0; r < 16; ++r) {
        float v = m[r];
#pragma unroll
        for (int q = 0; q < r; ++q) v -= S[r][q] * y[q];
        y[r] = v / S[r][r];
    }
#pragma unroll
    for (int r = 0; r < 16; ++r) {
        const int crow = k * 16 + r;
        Bt[(size_t)crow * 256 + (t ^ ((crow & 7) << 3))] = (__bf16)y[r];
    }
}

// ---------- kernel 2: X fp32 -> bf16, PRE-SWIZZLED (elem ^= (row&7)<<3), pad rows zero ----------
__global__ __launch_bounds__(256) void convert_X(const float* __restrict__ X,
                                                 __bf16* __restrict__ Xb) {
    size_t i = ((size_t)blockIdx.x * 256 + threadIdx.x) * 8;
    int n = (int)(i >> 8);
    int kk = (int)(i & 255);
    v8bf o;
    if (n < NPTS) {
        const float4* s4 = (const float4*)(X + i);
        float4 a = s4[0], b = s4[1];
        o[0] = (__bf16)a.x; o[1] = (__bf16)a.y; o[2] = (__bf16)a.z; o[3] = (__bf16)a.w;
        o[4] = (__bf16)b.x; o[5] = (__bf16)b.y; o[6] = (__bf16)b.z; o[7] = (__bf16)b.w;
    } else {
        for (int j = 0; j < 8; ++j) o[j] = (__bf16)0.0f;
    }
    *(v8bf*)(Xb + (size_t)n * 256 + (kk ^ ((n & 7) << 3))) = o;
}

// ---------- kernel 3: GEMM + fused quad/density epilogue ----------
// BK=64, double-buffered, swizzled LDS reads (conflict-free), XCD row-tile swizzle.
__global__ __launch_bounds__(256) void gemm_density(const __bf16* __restrict__ Xb,
                                                    const __bf16* __restrict__ Bt,
                                                    const float* __restrict__ cvec,
                                                    float* __restrict__ dens) {
    __shared__ __bf16 As[2][128 * 64];
    __shared__ __bf16 Bs[2][128 * 64];
    const int bid = blockIdx.x;
    const int xcd = bid & 7, j = bid >> 3;
    const int rt = xcd + ((j >> 3) << 3);   // 0..783: row-tile; 8 col-tiles stay on one XCD
    const int ct = j & 7;
    const int row0 = rt << 7, col0 = ct << 7;
    const int tid = threadIdx.x;
    const int wave = tid >> 6, lane = tid & 63;
    const int wm = wave >> 1, wn = wave & 1;
    const int lo = lane & 15, hi = lane >> 4;
    const int sw = lo & 7;

    v4f acc[4][4] = {};

#define STAGE(buf, kt) do {                                                          \
    _Pragma("unroll")                                                                \
    for (int q = 0; q < 4; ++q) {                                                    \
        const int r_ = (q << 5) + (tid >> 3);                                        \
        const int p_ = (tid & 7) << 3;                                               \
        gload_lds16(Xb + (size_t)(row0 + r_) * 256 + ((kt) << 6) + p_,               \
                    As[buf] + (((q << 8) + (wave << 6)) << 3));                      \
        gload_lds16(Bt + (size_t)(col0 + r_) * 256 + ((kt) << 6) + p_,               \
                    Bs[buf] + (((q << 8) + (wave << 6)) << 3));                      \
    }                                                                                \
} while (0)

    STAGE(0, 0);
    asm volatile("s_waitcnt vmcnt(0)" ::: "memory");
    __syncthreads();

    int cur = 0;
#pragma unroll
    for (int kt = 0; kt < 4; ++kt) {
        if (kt < 3) STAGE(cur ^ 1, kt + 1);   // prefetch next K-step

        v8bf af[2][4], bg[2][4];
#pragma unroll
        for (int ks = 0; ks < 2; ++ks) {
#pragma unroll
            for (int m = 0; m < 4; ++m) {
                const int rA = wm * 64 + m * 16 + lo;
                const int rB = wn * 64 + m * 16 + lo;
                const int cph = (((ks << 2) + hi) ^ sw) << 3;
                af[ks][m] = *(const v8bf*)&As[cur][rA * 64 + cph];
                bg[ks][m] = *(const v8bf*)&Bs[cur][rB * 64 + cph];
            }
        }
#pragma unroll
        for (int ks = 0; ks < 2; ++ks)
#pragma unroll
            for (int m = 0; m < 4; ++m)
#pragma unroll
                for (int n = 0; n < 4; ++n)
                    acc[m][n] = __builtin_amdgcn_mfma_f32_16x16x32_bf16(af[ks][m], bg[ks][n], acc[m][n], 0, 0, 0);

        if (kt < 3) {
            asm volatile("s_waitcnt vmcnt(0)" ::: "memory");
            __syncthreads();
            cur ^= 1;
        }
    }
#undef STAGE

    // epilogue: quad per (row, 16-col group) then density
#pragma unroll
    for (int m = 0; m < 4; ++m) {
        const int rowb = row0 + wm * 64 + m * 16 + hi * 4;
#pragma unroll
        for (int n = 0; n < 4; ++n) {
            const int kc = (col0 >> 4) + wn * 4 + n;
            v4f q = acc[m][n] * acc[m][n];
#pragma unroll
            for (int off = 1; off < 16; off <<= 1) {
                v4f t;
                t[0] = __shfl_xor(q[0], off);
                t[1] = __shfl_xor(q[1], off);
                t[2] = __shfl_xor(q[2], off);
                t[3] = __shfl_xor(q[3], off);
                q += t;
            }
            if (lo < 4) {
                const float quad = q[lo];
                const float d = cvec[kc] - 128.0f * logf(1.0f - quad);
                dens[(size_t)kc * NPAD + rowb + lo] = d;
            }
        }
    }
}

// ---------- kernel 4: logsumexp over k, global sum (branchless online) ----------
__global__ __launch_bounds__(256) void reduce_ll(const float* __restrict__ dens,
                                                 float* __restrict__ out) {
    const int n = blockIdx.x * 256 + threadIdx.x;
    float local = 0.0f;
    if (n < NPTS) {
        float m = dens[n];
        float s = 1.0f;
        for (int k = 1; k < 64; ++k) {
            float d = dens[(size_t)k * NPAD + n];
            float mn = fmaxf(m, d);
            s = s * __expf(m - mn) + __expf(d - mn);
            m = mn;
        }
        local = m + logf(s);
    }
    for (int off = 32; off; off >>= 1) local += __shfl_down(local, off);
    __shared__ float part[4];
    const int w = threadIdx.x >> 6, lane = threadIdx.x & 63;
    if (lane == 0) part[w] = local;
    __syncthreads();
    if (threadIdx.x == 0) atomicAdd(out, part[0] + part[1] + part[2] + part[3]);
}

extern "C" void kernel_launch(void* const* d_in, const int* in_sizes, int n_in,
                              void* d_out, int out_size, void* d_ws, size_t ws_size,
                              hipStream_t stream) {
    const float* X  = (const float*)d_in[0];
    const float* M  = (const float*)d_in[1];
    const float* pi = (const float*)d_in[2];
    float* out = (float*)d_out;

    char* ws = (char*)d_ws;
    __bf16* Xb    = (__bf16*)ws;                          // 100352*256*2 = 51,380,224
    __bf16* Bt    = (__bf16*)(ws + 51380224);             // 1024*256*2   =    524,288
    float*  dens  = (float*)(ws + 51904512);              // 64*100352*4  = 25,690,112
    float*  cvec  = (float*)(ws + 77594624);              // 256 B

    const double half_p = 128.0;
    const float logSA = (float)(lgamma(half_p) - log(2.0) - half_p * log(M_PI));

    hipMemsetAsync(d_out, 0, sizeof(float), stream);
    prep_comp<<<64, 256, 0, stream>>>(M, pi, Bt, cvec, logSA);
    convert_X<<<12544, 256, 0, stream>>>(X, Xb);          // 100352*256/2048
    gemm_density<<<6272, 256, 0, stream>>>(Xb, Bt, cvec, dens);   // 784*8 tiles
    reduce_ll<<<391, 256, 0, stream>>>(dens, out);
}